// Round 1
// baseline (264.325 us; speedup 1.0000x reference)
//
#include <hip/hip_runtime.h>
#include <hip/hip_bf16.h>
#include <cstdint>

// ---------- types ----------
typedef __bf16 bf16x8 __attribute__((ext_vector_type(8)));
typedef float f32x4 __attribute__((ext_vector_type(4)));

__device__ __forceinline__ float bf2f(unsigned short u) {
  union { unsigned int i; float f; } x; x.i = ((unsigned int)u) << 16; return x.f;
}
__device__ __forceinline__ unsigned short f2bf(float f) {
  __hip_bfloat16 h = __float2bfloat16(f);
  return __builtin_bit_cast(unsigned short, h);
}

// async global->LDS, 16B per lane. LDS dest is wave-uniform base + lane*16.
__device__ __forceinline__ void gload_lds16(const void* g, void* l) {
  auto gp = reinterpret_cast<__attribute__((address_space(1))) char*>(
      reinterpret_cast<uintptr_t>(g));
  auto lp = reinterpret_cast<__attribute__((address_space(3))) char*>(
      reinterpret_cast<uintptr_t>(l));
  __builtin_amdgcn_global_load_lds(gp, lp, 16, 0, 0);
}

// ---------- fp32 -> bf16 elementwise (x) ----------
__global__ __launch_bounds__(256) void cvt_f32_to_bf16(
    const float* __restrict__ in, unsigned short* __restrict__ out, long n4) {
  long i = (long)blockIdx.x * 256 + threadIdx.x;
  if (i >= n4) return;
  const float4 v = reinterpret_cast<const float4*>(in)[i];
  ushort4 o;
  o.x = f2bf(v.x); o.y = f2bf(v.y); o.z = f2bf(v.z); o.w = f2bf(v.w);
  reinterpret_cast<ushort4*>(out)[i] = o;
}

// ---------- transpose (+convert) to bf16: out[c][r] = in[r][c] ----------
template <typename InT>
__global__ void transpose_to_bf16(const InT* __restrict__ in,
                                  unsigned short* __restrict__ out,
                                  int rows, int cols, long sIn, long sOut) {
  in  += (long)blockIdx.z * sIn;
  out += (long)blockIdx.z * sOut;
  __shared__ float tile[32][33];
  const int c0 = blockIdx.x * 32, r0 = blockIdx.y * 32;
  const InT e = in[(size_t)(r0 + threadIdx.y) * cols + c0 + threadIdx.x];
  float v;
  if constexpr (sizeof(InT) == 4) v = (float)e; else v = bf2f(e);
  tile[threadIdx.y][threadIdx.x] = v;
  __syncthreads();
  out[(size_t)(c0 + threadIdx.y) * rows + r0 + threadIdx.x] =
      f2bf(tile[threadIdx.x][threadIdx.y]);
}

// ---------- bf16 GEMM: C[M][N] = scale * (A[M][K] @ Bt[N][K]^T) + bias ----------
// m97 structure: 128x128 tile, BK=64, 4 waves (2x2 of 64x64), mfma 16x16x32 bf16,
// global_load_lds width 16. All dims must be multiples of 128 (M,N) / 64 (K).
template <typename OutT, bool HAS_BIAS>
__global__ __launch_bounds__(256, 2) void gemm_bt(
    const unsigned short* __restrict__ A,
    const unsigned short* __restrict__ Bt,
    OutT* __restrict__ C,
    const float* __restrict__ bias,
    int M, int N, int K, int lda, int ldb, int ldc,
    float scale, long sA, long sB, long sC) {
  A  += (long)blockIdx.z * sA;
  Bt += (long)blockIdx.z * sB;
  C  += (long)blockIdx.z * sC;
  const int n0 = blockIdx.x * 128;
  const int m0 = blockIdx.y * 128;
  __shared__ __attribute__((aligned(16))) unsigned short As[128 * 64];
  __shared__ __attribute__((aligned(16))) unsigned short Bs[128 * 64];
  const int t = threadIdx.x;
  const int lane = t & 63;
  const int wr = t >> 7;        // wave row (0..1)
  const int wc = (t >> 6) & 1;  // wave col (0..1)

  f32x4 acc[4][4];
  const f32x4 vzero = {0.f, 0.f, 0.f, 0.f};
#pragma unroll
  for (int m = 0; m < 4; ++m)
#pragma unroll
    for (int n = 0; n < 4; ++n) acc[m][n] = vzero;

  for (int k0 = 0; k0 < K; k0 += 64) {
#pragma unroll
    for (int i = 0; i < 4; ++i) {
      const int idx = (i * 256 + t) * 8;  // bf16 element index within 128x64 tile
      const int r = idx >> 6;
      const int c = idx & 63;
      // wave-uniform LDS base (t & 192 == wave*64); HW adds lane*16B
      gload_lds16(A + (size_t)(m0 + r) * lda + k0 + c,
                  As + (size_t)(i * 256 + (t & 192)) * 8);
      gload_lds16(Bt + (size_t)(n0 + r) * ldb + k0 + c,
                  Bs + (size_t)(i * 256 + (t & 192)) * 8);
    }
    __syncthreads();
    const unsigned short* aw = As + (wr * 64 + (lane & 15)) * 64;
    const unsigned short* bw = Bs + (wc * 64 + (lane & 15)) * 64;
    const int ks = (lane >> 4) * 8;
#pragma unroll
    for (int kk = 0; kk < 2; ++kk) {
      bf16x8 af[4], bg[4];
#pragma unroll
      for (int m = 0; m < 4; ++m)
        af[m] = *reinterpret_cast<const bf16x8*>(aw + m * 16 * 64 + kk * 32 + ks);
#pragma unroll
      for (int n = 0; n < 4; ++n)
        bg[n] = *reinterpret_cast<const bf16x8*>(bw + n * 16 * 64 + kk * 32 + ks);
#pragma unroll
      for (int m = 0; m < 4; ++m)
#pragma unroll
        for (int n = 0; n < 4; ++n)
          acc[m][n] = __builtin_amdgcn_mfma_f32_16x16x32_bf16(af[m], bg[n],
                                                              acc[m][n], 0, 0, 0);
    }
    __syncthreads();
  }

  // C/D layout (m89-verified): col = lane&15, row = (lane>>4)*4 + i
  const int crow0 = m0 + wr * 64 + ((lane >> 4) << 2);
  const int ccol0 = n0 + wc * 64 + (lane & 15);
#pragma unroll
  for (int m = 0; m < 4; ++m) {
#pragma unroll
    for (int n = 0; n < 4; ++n) {
      const int col = ccol0 + n * 16;
      const float bb = HAS_BIAS ? bias[col] : 0.f;
#pragma unroll
      for (int i = 0; i < 4; ++i) {
        const int row = crow0 + m * 16 + i;
        const float v = acc[m][n][i] * scale + bb;
        if constexpr (sizeof(OutT) == 2) {
          C[(size_t)row * ldc + col] = (OutT)f2bf(v);
        } else {
          C[(size_t)row * ldc + col] = (OutT)v;
        }
      }
    }
  }
}

// ---------- row softmax, in place, bf16, one block per row (S=2048) ----------
__global__ __launch_bounds__(256) void softmax_inplace(
    unsigned short* __restrict__ P, int S) {
  const size_t row = blockIdx.x;
  unsigned short* p = P + row * (size_t)S;
  const int t = threadIdx.x;
  const int lane = t & 63, w = t >> 6;
  const uint4 raw = reinterpret_cast<const uint4*>(p)[t];
  unsigned int u[4] = {raw.x, raw.y, raw.z, raw.w};
  float v[8];
#pragma unroll
  for (int j = 0; j < 4; ++j) {
    v[2 * j]     = bf2f((unsigned short)(u[j] & 0xffffu));
    v[2 * j + 1] = bf2f((unsigned short)(u[j] >> 16));
  }
  float mx = v[0];
#pragma unroll
  for (int j = 1; j < 8; ++j) mx = fmaxf(mx, v[j]);
#pragma unroll
  for (int off = 32; off >= 1; off >>= 1) mx = fmaxf(mx, __shfl_xor(mx, off, 64));
  __shared__ float red[4];
  if (lane == 0) red[w] = mx;
  __syncthreads();
  mx = fmaxf(fmaxf(red[0], red[1]), fmaxf(red[2], red[3]));
  float e[8];
  float s = 0.f;
#pragma unroll
  for (int j = 0; j < 8; ++j) { e[j] = __expf(v[j] - mx); s += e[j]; }
#pragma unroll
  for (int off = 32; off >= 1; off >>= 1) s += __shfl_xor(s, off, 64);
  __syncthreads();
  if (lane == 0) red[w] = s;
  __syncthreads();
  s = red[0] + red[1] + red[2] + red[3];
  const float inv = 1.f / s;
  unsigned int o[4];
#pragma unroll
  for (int j = 0; j < 4; ++j)
    o[j] = (unsigned int)f2bf(e[2 * j] * inv) |
           ((unsigned int)f2bf(e[2 * j + 1] * inv) << 16);
  uint4 ov; ov.x = o[0]; ov.y = o[1]; ov.z = o[2]; ov.w = o[3];
  reinterpret_cast<uint4*>(p)[t] = ov;
}

// ---------- launch ----------
extern "C" void kernel_launch(void* const* d_in, const int* in_sizes, int n_in,
                              void* d_out, int out_size, void* d_ws, size_t ws_size,
                              hipStream_t stream) {
  (void)in_sizes; (void)n_in; (void)out_size; (void)ws_size;
  const float* x  = (const float*)d_in[0];
  const float* Wq = (const float*)d_in[1];
  const float* bq = (const float*)d_in[2];
  const float* Wk = (const float*)d_in[3];
  const float* bk = (const float*)d_in[4];
  const float* Wv = (const float*)d_in[5];
  const float* bv = (const float*)d_in[6];
  const float* Wo = (const float*)d_in[7];
  const float* bo = (const float*)d_in[8];
  float* out = (float*)d_out;

  constexpr int B = 4, S = 2048, D = 1024;
  constexpr long BS = (long)B * S;  // 8192
  constexpr size_t MB = 1ull << 20;
  char* ws = (char*)d_ws;
  // workspace map (120 MB total):
  unsigned short* xb  = (unsigned short*)(ws + 0);        // 16MB, dead after V-proj
  unsigned short* Wqt = (unsigned short*)(ws + 16 * MB);  // 2MB each
  unsigned short* Wkt = (unsigned short*)(ws + 18 * MB);
  unsigned short* Wvt = (unsigned short*)(ws + 20 * MB);
  unsigned short* Wot = (unsigned short*)(ws + 22 * MB);
  unsigned short* Q   = (unsigned short*)(ws + 24 * MB);  // 16MB
  unsigned short* Kb  = (unsigned short*)(ws + 40 * MB);  // 16MB
  unsigned short* V   = (unsigned short*)(ws + 56 * MB);  // 16MB
  unsigned short* Vt  = (unsigned short*)(ws + 72 * MB);  // 16MB
  unsigned short* Sc  = (unsigned short*)(ws + 88 * MB);  // 32MB (scores, then P)
  unsigned short* AO  = (unsigned short*)(ws + 0);        // aliases xb (dead)

  const float scale = 0.03125f;  // 1/sqrt(1024)
  const dim3 tb(32, 32);

  cvt_f32_to_bf16<<<(BS * D / 4 + 255) / 256, 256, 0, stream>>>(x, xb, BS * D / 4);
  transpose_to_bf16<float><<<dim3(32, 32, 1), tb, 0, stream>>>(Wq, Wqt, D, D, 0, 0);
  transpose_to_bf16<float><<<dim3(32, 32, 1), tb, 0, stream>>>(Wk, Wkt, D, D, 0, 0);
  transpose_to_bf16<float><<<dim3(32, 32, 1), tb, 0, stream>>>(Wv, Wvt, D, D, 0, 0);
  transpose_to_bf16<float><<<dim3(32, 32, 1), tb, 0, stream>>>(Wo, Wot, D, D, 0, 0);

  // Q/K/V projections: [8192,1024] = xb @ Wt^T + b
  gemm_bt<unsigned short, true><<<dim3(D / 128, BS / 128, 1), 256, 0, stream>>>(
      xb, Wqt, Q, bq, BS, D, D, D, D, D, 1.f, 0, 0, 0);
  gemm_bt<unsigned short, true><<<dim3(D / 128, BS / 128, 1), 256, 0, stream>>>(
      xb, Wkt, Kb, bk, BS, D, D, D, D, D, 1.f, 0, 0, 0);
  gemm_bt<unsigned short, true><<<dim3(D / 128, BS / 128, 1), 256, 0, stream>>>(
      xb, Wvt, V, bv, BS, D, D, D, D, D, 1.f, 0, 0, 0);

  // V^T per batch: Vt[b][d][s] = V[b][s][d]
  transpose_to_bf16<unsigned short><<<dim3(D / 32, S / 32, B), tb, 0, stream>>>(
      V, Vt, S, D, (long)S * D, (long)S * D);

  // scores[b] = scale * Q[b] @ K[b]^T   [2048 x 2048]
  gemm_bt<unsigned short, false><<<dim3(S / 128, S / 128, B), 256, 0, stream>>>(
      Q, Kb, Sc, nullptr, S, S, D, D, D, S, scale,
      (long)S * D, (long)S * D, (long)S * S);

  softmax_inplace<<<B * S, 256, 0, stream>>>(Sc, S);

  // attn_out[b] = P[b] @ V[b]  via Vt:  [2048 x 1024], K-dim 2048
  gemm_bt<unsigned short, false><<<dim3(D / 128, S / 128, B), 256, 0, stream>>>(
      Sc, Vt, AO, nullptr, S, D, S, S, S, D, 1.f,
      (long)S * S, (long)D * S, (long)S * D);

  // out = AO @ Wo^T + bo  (fp32 output)
  gemm_bt<float, true><<<dim3(D / 128, BS / 128, 1), 256, 0, stream>>>(
      AO, Wot, out, bo, BS, D, D, D, D, D, 1.f, 0, 0, 0);
}

// Round 2
// 249.450 us; speedup vs baseline: 1.0596x; 1.0596x over previous
//
#include <hip/hip_runtime.h>
#include <hip/hip_bf16.h>
#include <cstdint>

typedef __bf16 bf16x8 __attribute__((ext_vector_type(8)));
typedef float f32x4 __attribute__((ext_vector_type(4)));
typedef unsigned short ushort_t;

__device__ __forceinline__ float bf2f(unsigned short u) {
  union { unsigned int i; float f; } x; x.i = ((unsigned int)u) << 16; return x.f;
}
__device__ __forceinline__ unsigned short f2bf(float f) {
  __hip_bfloat16 h = __float2bfloat16(f);
  return __builtin_bit_cast(unsigned short, h);
}

// async global->LDS, 16B/lane. LDS dest = wave-uniform base + lane*16.
__device__ __forceinline__ void gload_lds16(const void* g, void* l) {
  auto gp = reinterpret_cast<__attribute__((address_space(1))) char*>(
      reinterpret_cast<uintptr_t>(g));
  auto lp = reinterpret_cast<__attribute__((address_space(3))) char*>(
      reinterpret_cast<uintptr_t>(l));
  __builtin_amdgcn_global_load_lds(gp, lp, 16, 0, 0);
}

#define SB() __builtin_amdgcn_sched_barrier(0)
#define BAR()                         \
  do {                                \
    SB();                             \
    __builtin_amdgcn_s_barrier();     \
    SB();                             \
  } while (0)
#define LGKM0()                                          \
  do {                                                   \
    asm volatile("s_waitcnt lgkmcnt(0)" ::: "memory");   \
    SB();                                                \
  } while (0)

// ---------- fp32 -> bf16 ----------
__global__ __launch_bounds__(256) void cvt_f32_to_bf16(
    const float* __restrict__ in, unsigned short* __restrict__ out, long n4) {
  long i = (long)blockIdx.x * 256 + threadIdx.x;
  if (i >= n4) return;
  const float4 v = reinterpret_cast<const float4*>(in)[i];
  ushort4 o;
  o.x = f2bf(v.x); o.y = f2bf(v.y); o.z = f2bf(v.z); o.w = f2bf(v.w);
  reinterpret_cast<ushort4*>(out)[i] = o;
}

// ---------- transpose (+convert) to bf16: out[c][r] = in[r][c] ----------
template <typename InT>
__global__ void transpose_to_bf16(const InT* __restrict__ in,
                                  unsigned short* __restrict__ out,
                                  int ldIn, int ldOut, long sIn, long sOut) {
  in  += (long)blockIdx.z * sIn;
  out += (long)blockIdx.z * sOut;
  __shared__ float tile[32][33];
  const int c0 = blockIdx.x * 32, r0 = blockIdx.y * 32;
  const InT e = in[(size_t)(r0 + threadIdx.y) * ldIn + c0 + threadIdx.x];
  float v;
  if constexpr (sizeof(InT) == 4) v = (float)e; else v = bf2f(e);
  tile[threadIdx.y][threadIdx.x] = v;
  __syncthreads();
  out[(size_t)(c0 + threadIdx.y) * ldOut + r0 + threadIdx.x] =
      f2bf(tile[threadIdx.x][threadIdx.y]);
}

__global__ void concat_bias3(const float* a, const float* b, const float* c,
                             float* o) {
  int i = blockIdx.x * 256 + threadIdx.x;
  if (i >= 3072) return;
  o[i] = (i < 1024) ? a[i] : (i < 2048 ? b[i - 1024] : c[i - 2048]);
}

// =====================================================================
// 256x256 8-phase bf16 GEMM (m201 template, plain HIP).
// C[M][N] = scale*(A[M][K] @ Bt[N][K]^T) + bias.  M,N % 256 == 0, K % 64 == 0.
// 512 threads = 8 waves (2M x 4N); per-wave out 128x64; BK=64; LDS 128KB dbuf.
// T2 swizzle: linear gload_lds dest + XOR'd global source + XOR'd ds_read.
// =====================================================================

// stage one half-tile (128 rows x 64 cols bf16 = 16KB): 2 gload_lds16/thread.
// half h of A: rows {0-63,128-191} (h=0, read at phase1) / {64-127,192-255} (h=1, phase3)
// half h of B: rows r with ((r>>5)&1)==h   (h=0 read at phase1, h=1 at phase2)
#define STAGE_A(gbase, ld, ldsbase, h)                                        \
  {                                                                           \
    _Pragma("unroll") for (int l_ = 0; l_ < 2; ++l_) {                        \
      const int seg_ = (w << 1) + l_;                                         \
      const int r0_ = ((seg_ >> 3) << 7) + ((h) << 6) + ((seg_ & 7) << 3);    \
      const int gr_ = r0_ + (lane >> 3);                                      \
      const int sc_ = ((lane & 7) ^ (lane >> 3)) << 3;                        \
      gload_lds16((gbase) + (size_t)gr_ * (ld) + sc_, (ldsbase) + r0_ * 64);  \
    }                                                                         \
  }
#define STAGE_B(gbase, ld, ldsbase, h)                                        \
  {                                                                           \
    _Pragma("unroll") for (int l_ = 0; l_ < 2; ++l_) {                        \
      const int seg_ = (w << 1) + l_;                                         \
      const int r0_ = ((seg_ >> 2) << 6) + ((h) << 5) + ((seg_ & 3) << 3);    \
      const int gr_ = r0_ + (lane >> 3);                                      \
      const int sc_ = ((lane & 7) ^ (lane >> 3)) << 3;                        \
      gload_lds16((gbase) + (size_t)gr_ * (ld) + sc_, (ldsbase) + r0_ * 64);  \
    }                                                                         \
  }

// ds_read one 64-row (A) / 32-row (B) subtile into fragments, swizzled.
#define LDA_FRAG(dst, tile, rbase)                                            \
  _Pragma("unroll") for (int m_ = 0; m_ < 4; ++m_)                            \
  _Pragma("unroll") for (int kk_ = 0; kk_ < 2; ++kk_) {                       \
    const int row_ = (rbase) + (m_ << 4) + (lane & 15);                       \
    const int ch_ = ((kk_ << 2) + (lane >> 4)) ^ (lane & 7);                  \
    dst[m_][kk_] =                                                            \
        *reinterpret_cast<const bf16x8*>((tile) + row_ * 64 + (ch_ << 3));    \
  }
#define LDB_FRAG(dst, tile, rbase)                                            \
  _Pragma("unroll") for (int n_ = 0; n_ < 2; ++n_)                            \
  _Pragma("unroll") for (int kk_ = 0; kk_ < 2; ++kk_) {                       \
    const int row_ = (rbase) + (n_ << 4) + (lane & 15);                       \
    const int ch_ = ((kk_ << 2) + (lane >> 4)) ^ (lane & 7);                  \
    dst[n_][kk_] =                                                            \
        *reinterpret_cast<const bf16x8*>((tile) + row_ * 64 + (ch_ << 3));    \
  }

#define MFMA_QUAD(a_, b_, af_, bf_)                                           \
  __builtin_amdgcn_s_setprio(1);                                              \
  _Pragma("unroll") for (int m_ = 0; m_ < 4; ++m_)                            \
  _Pragma("unroll") for (int n_ = 0; n_ < 2; ++n_)                            \
  _Pragma("unroll") for (int kk_ = 0; kk_ < 2; ++kk_)                         \
      acc[(a_) * 4 + m_][(b_) * 2 + n_] =                                     \
          __builtin_amdgcn_mfma_f32_16x16x32_bf16(                            \
              af_[m_][kk_], bf_[n_][kk_], acc[(a_) * 4 + m_][(b_) * 2 + n_],  \
              0, 0, 0);                                                       \
  __builtin_amdgcn_s_setprio(0);

template <typename OutT, bool HAS_BIAS>
__global__ __launch_bounds__(512, 2) void gemm256(
    const unsigned short* __restrict__ A,
    const unsigned short* __restrict__ Bt,
    OutT* __restrict__ C,
    const float* __restrict__ bias,
    int K, int lda, int ldb, int ldc, float scale,
    long sA, long sB, long sC) {
  A  += (long)blockIdx.z * sA;
  Bt += (long)blockIdx.z * sB;
  C  += (long)blockIdx.z * sC;
  const int n0 = blockIdx.x << 8;
  const int m0 = blockIdx.y << 8;
  __shared__ __attribute__((aligned(16))) unsigned short lds[2 * 32768];
  const int t = threadIdx.x;
  const int lane = t & 63;
  const int w = t >> 6;
  const int wm = w >> 2, wn = w & 3;
  const unsigned short* gA = A + (size_t)m0 * lda;
  const unsigned short* gB = Bt + (size_t)n0 * ldb;
  const int NT = K >> 6;

  f32x4 acc[8][4];
  const f32x4 vz = {0.f, 0.f, 0.f, 0.f};
#pragma unroll
  for (int i = 0; i < 8; ++i)
#pragma unroll
    for (int j = 0; j < 4; ++j) acc[i][j] = vz;

  // ---- prologue: tile0 all 4 halves, tile1 halves {Ah0,Bh0,Bh1} ----
  {
    unsigned short* a0 = lds;
    unsigned short* b0t = lds + 16384;
    STAGE_A(gA, lda, a0, 0);
    STAGE_B(gB, ldb, b0t, 0);
    STAGE_B(gB, ldb, b0t, 1);
    STAGE_A(gA, lda, a0, 1);
    if (NT > 1) {
      unsigned short* a1 = lds + 32768;
      unsigned short* b1t = lds + 32768 + 16384;
      STAGE_A(gA + 64, lda, a1, 0);
      STAGE_B(gB + 64, ldb, b1t, 0);
      STAGE_B(gB + 64, ldb, b1t, 1);
      asm volatile("s_waitcnt vmcnt(6)" ::: "memory");
    } else {
      asm volatile("s_waitcnt vmcnt(0)" ::: "memory");
    }
  }
  BAR();

  for (int kt = 0; kt < NT; ++kt) {
    unsigned short* at = lds + ((kt & 1) << 15);
    unsigned short* bt = at + 16384;
    unsigned short* atN = lds + (((kt + 1) & 1) << 15);
    const unsigned short* gA1 = gA + (size_t)(kt + 1) * 64;
    const unsigned short* gA2 = gA + (size_t)(kt + 2) * 64;
    const unsigned short* gB2 = gB + (size_t)(kt + 2) * 64;
    const bool st1 = kt + 1 < NT, st2 = kt + 2 < NT;

    bf16x8 af[4][2], b0[2][2], b1[2][2];

    // -- phase 1: read A-sub0 (8) + B-sub0 (4); stage Ah1(t+1) --
    LDA_FRAG(af, at, (wm << 7));
    LDB_FRAG(b0, bt, (wn << 6));
    if (st1) STAGE_A(gA1, lda, atN, 1);
    BAR();
    LGKM0();
    MFMA_QUAD(0, 0, af, b0);
    BAR();

    // -- phase 2: read B-sub1 (4); stage Ah0(t+2) --
    LDB_FRAG(b1, bt, (wn << 6) + 32);
    if (st2) STAGE_A(gA2, lda, at, 0);
    BAR();
    LGKM0();
    MFMA_QUAD(0, 1, af, b1);
    BAR();

    // -- phase 3: read A-sub1 (8); stage Bh0(t+2) --
    LDA_FRAG(af, at, (wm << 7) + 64);
    if (st2) STAGE_B(gB2, ldb, bt, 0);
    BAR();
    LGKM0();
    MFMA_QUAD(1, 0, af, b0);
    BAR();

    // -- phase 4: stage Bh1(t+2); counted vmcnt --
    if (st2) STAGE_B(gB2, ldb, bt, 1);
    if (kt < NT - 3) {
      asm volatile("s_waitcnt vmcnt(6)" ::: "memory");
    } else {
      asm volatile("s_waitcnt vmcnt(0)" ::: "memory");
    }
    BAR();
    MFMA_QUAD(1, 1, af, b1);
    BAR();
  }

  // ---- epilogue: C/D layout col=lane&15, row=(lane>>4)*4+i ----
  const int crow0 = m0 + (wm << 7) + ((lane >> 4) << 2);
  const int ccol0 = n0 + (wn << 6) + (lane & 15);
#pragma unroll
  for (int mf = 0; mf < 8; ++mf) {
#pragma unroll
    for (int nf = 0; nf < 4; ++nf) {
      const int col = ccol0 + (nf << 4);
      const float bb = HAS_BIAS ? bias[col] : 0.f;
#pragma unroll
      for (int i = 0; i < 4; ++i) {
        const int row = crow0 + (mf << 4) + i;
        const float v = acc[mf][nf][i] * scale + bb;
        if constexpr (sizeof(OutT) == 2) {
          C[(size_t)row * ldc + col] = (OutT)f2bf(v);
        } else {
          C[(size_t)row * ldc + col] = (OutT)v;
        }
      }
    }
  }
}

// ---------- row softmax, in place, bf16, one block per row ----------
__global__ __launch_bounds__(256) void softmax_inplace(
    unsigned short* __restrict__ P, int S) {
  const size_t row = blockIdx.x;
  unsigned short* p = P + row * (size_t)S;
  const int t = threadIdx.x;
  const int lane = t & 63, w = t >> 6;
  const uint4 raw = reinterpret_cast<const uint4*>(p)[t];
  unsigned int u[4] = {raw.x, raw.y, raw.z, raw.w};
  float v[8];
#pragma unroll
  for (int j = 0; j < 4; ++j) {
    v[2 * j]     = bf2f((unsigned short)(u[j] & 0xffffu));
    v[2 * j + 1] = bf2f((unsigned short)(u[j] >> 16));
  }
  float mx = v[0];
#pragma unroll
  for (int j = 1; j < 8; ++j) mx = fmaxf(mx, v[j]);
#pragma unroll
  for (int off = 32; off >= 1; off >>= 1) mx = fmaxf(mx, __shfl_xor(mx, off, 64));
  __shared__ float red[4];
  if (lane == 0) red[w] = mx;
  __syncthreads();
  mx = fmaxf(fmaxf(red[0], red[1]), fmaxf(red[2], red[3]));
  float e[8];
  float s = 0.f;
#pragma unroll
  for (int j = 0; j < 8; ++j) { e[j] = __expf(v[j] - mx); s += e[j]; }
#pragma unroll
  for (int off = 32; off >= 1; off >>= 1) s += __shfl_xor(s, off, 64);
  __syncthreads();
  if (lane == 0) red[w] = s;
  __syncthreads();
  s = red[0] + red[1] + red[2] + red[3];
  const float inv = 1.f / s;
  unsigned int o[4];
#pragma unroll
  for (int j = 0; j < 4; ++j)
    o[j] = (unsigned int)f2bf(e[2 * j] * inv) |
           ((unsigned int)f2bf(e[2 * j + 1] * inv) << 16);
  uint4 ov; ov.x = o[0]; ov.y = o[1]; ov.z = o[2]; ov.w = o[3];
  reinterpret_cast<uint4*>(p)[t] = ov;
}

// ---------- launch ----------
extern "C" void kernel_launch(void* const* d_in, const int* in_sizes, int n_in,
                              void* d_out, int out_size, void* d_ws, size_t ws_size,
                              hipStream_t stream) {
  (void)in_sizes; (void)n_in; (void)out_size; (void)ws_size;
  const float* x  = (const float*)d_in[0];
  const float* Wq = (const float*)d_in[1];
  const float* bq = (const float*)d_in[2];
  const float* Wk = (const float*)d_in[3];
  const float* bk = (const float*)d_in[4];
  const float* Wv = (const float*)d_in[5];
  const float* bv = (const float*)d_in[6];
  const float* Wo = (const float*)d_in[7];
  const float* bo = (const float*)d_in[8];
  float* out = (float*)d_out;

  constexpr int B = 4, S = 2048, D = 1024;
  constexpr long BS = (long)B * S;  // 8192
  constexpr size_t MB = 1ull << 20;
  char* ws = (char*)d_ws;
  // workspace map (105 MB):
  unsigned short* xb    = (unsigned short*)(ws + 0);        // 16MB (dead after QKV gemm)
  unsigned short* Wqkvt = (unsigned short*)(ws + 16 * MB);  // 6MB  [3072][1024]
  unsigned short* Wot   = (unsigned short*)(ws + 22 * MB);  // 2MB
  float*          bqkv  = (float*)(ws + 24 * MB);           // 12KB
  unsigned short* QKVc  = (unsigned short*)(ws + 25 * MB);  // 48MB [8192][3072]
  unsigned short* Vt    = (unsigned short*)(ws + 0);        // 16MB (over xb)
  unsigned short* Sc    = (unsigned short*)(ws + 73 * MB);  // 32MB
  unsigned short* AO    = (unsigned short*)(ws + 25 * MB);  // 16MB (over QKVc head)

  const float scale = 0.03125f;  // 1/sqrt(1024)
  const dim3 tb(32, 32);

  cvt_f32_to_bf16<<<(BS * D / 4 + 255) / 256, 256, 0, stream>>>(x, xb, BS * D / 4);
  // weight transposes into concatenated QKV + O
  transpose_to_bf16<float><<<dim3(32, 32, 1), tb, 0, stream>>>(
      Wq, Wqkvt + 0 * D * D, D, D, 0, 0);
  transpose_to_bf16<float><<<dim3(32, 32, 1), tb, 0, stream>>>(
      Wk, Wqkvt + 1 * D * D, D, D, 0, 0);
  transpose_to_bf16<float><<<dim3(32, 32, 1), tb, 0, stream>>>(
      Wv, Wqkvt + 2 * D * D, D, D, 0, 0);
  transpose_to_bf16<float><<<dim3(32, 32, 1), tb, 0, stream>>>(
      Wo, Wot, D, D, 0, 0);
  concat_bias3<<<12, 256, 0, stream>>>(bq, bk, bv, bqkv);

  // fused QKV projection: [8192,3072] = xb @ Wqkvt^T + bqkv
  gemm256<unsigned short, true><<<dim3(3072 / 256, BS / 256, 1), 512, 0, stream>>>(
      xb, Wqkvt, QKVc, bqkv, D, D, D, 3072, 1.f, 0, 0, 0);

  // V^T per batch: Vt[b][d][s] = QKVc[b*S+s][2048+d]
  transpose_to_bf16<unsigned short><<<dim3(D / 32, S / 32, B), tb, 0, stream>>>(
      QKVc + 2048, Vt, 3072, S, (long)S * 3072, (long)D * S);

  // scores[b] = scale * Q[b] @ K[b]^T   [2048 x 2048]
  gemm256<unsigned short, false><<<dim3(S / 256, S / 256, B), 512, 0, stream>>>(
      QKVc + 0, QKVc + 1024, Sc, nullptr, D, 3072, 3072, S, scale,
      (long)S * 3072, (long)S * 3072, (long)S * S);

  softmax_inplace<<<B * S, 256, 0, stream>>>(Sc, S);

  // attn_out[b] = P[b] @ V[b]  via Vt: [2048 x 1024], K-dim 2048
  gemm256<unsigned short, false><<<dim3(D / 256, S / 256, B), 512, 0, stream>>>(
      Sc, Vt, AO, nullptr, S, S, S, D, 1.f,
      (long)S * S, (long)D * S, (long)S * D);

  // out = AO @ Wot^T + bo  (fp32 output)
  gemm256<float, true><<<dim3(D / 256, BS / 256, 1), 512, 0, stream>>>(
      AO, Wot, out, bo, D, D, D, D, 1.f, 0, 0, 0);
}

// Round 3
// 204.412 us; speedup vs baseline: 1.2931x; 1.2203x over previous
//
#include <hip/hip_runtime.h>
#include <hip/hip_bf16.h>
#include <cstdint>

typedef __bf16 bf16x8 __attribute__((ext_vector_type(8)));
typedef float f32x4 __attribute__((ext_vector_type(4)));

__device__ __forceinline__ float bf2f(unsigned short u) {
  union { unsigned int i; float f; } x; x.i = ((unsigned int)u) << 16; return x.f;
}
__device__ __forceinline__ unsigned short f2bf(float f) {
  __hip_bfloat16 h = __float2bfloat16(f);
  return __builtin_bit_cast(unsigned short, h);
}

__device__ __forceinline__ void gload_lds16(const void* g, void* l) {
  auto gp = reinterpret_cast<__attribute__((address_space(1))) char*>(
      reinterpret_cast<uintptr_t>(g));
  auto lp = reinterpret_cast<__attribute__((address_space(3))) char*>(
      reinterpret_cast<uintptr_t>(l));
  __builtin_amdgcn_global_load_lds(gp, lp, 16, 0, 0);
}

#define SB() __builtin_amdgcn_sched_barrier(0)
#define BAR()                         \
  do {                                \
    SB();                             \
    __builtin_amdgcn_s_barrier();     \
    SB();                             \
  } while (0)
#define LGKM0()                                          \
  do {                                                   \
    asm volatile("s_waitcnt lgkmcnt(0)" ::: "memory");   \
    SB();                                                \
  } while (0)

// T1: bijective XCD-aware block swizzle (requires total blocks % 8 == 0)
__device__ __forceinline__ void xcd_swz(int& bx, int& by, int& bz) {
  const int gx = gridDim.x, gy = gridDim.y;
  const int n = gx * gy * (int)gridDim.z;
  int lin = blockIdx.x + gx * (blockIdx.y + gy * blockIdx.z);
  lin = (lin & 7) * (n >> 3) + (lin >> 3);
  bx = lin % gx; lin /= gx;
  by = lin % gy; bz = lin / gy;
}

// ---------- fp32 -> bf16 ----------
__global__ __launch_bounds__(256) void cvt_f32_to_bf16(
    const float* __restrict__ in, unsigned short* __restrict__ out, long n4) {
  long i = (long)blockIdx.x * 256 + threadIdx.x;
  if (i >= n4) return;
  const float4 v = reinterpret_cast<const float4*>(in)[i];
  ushort4 o;
  o.x = f2bf(v.x); o.y = f2bf(v.y); o.z = f2bf(v.z); o.w = f2bf(v.w);
  reinterpret_cast<ushort4*>(out)[i] = o;
}

// ---------- all 4 weight transposes in one launch: Wall[z][n][k] = W_z[k][n] ----------
__global__ void transpose_w4(const float* __restrict__ w0,
                             const float* __restrict__ w1,
                             const float* __restrict__ w2,
                             const float* __restrict__ w3,
                             unsigned short* __restrict__ out) {
  const int z = blockIdx.z;
  const float* in = (z == 0) ? w0 : (z == 1) ? w1 : (z == 2) ? w2 : w3;
  out += (size_t)z * 1024 * 1024;
  __shared__ float tile[32][33];
  const int c0 = blockIdx.x * 32, r0 = blockIdx.y * 32;
  tile[threadIdx.y][threadIdx.x] =
      in[(size_t)(r0 + threadIdx.y) * 1024 + c0 + threadIdx.x];
  __syncthreads();
  out[(size_t)(c0 + threadIdx.y) * 1024 + r0 + threadIdx.x] =
      f2bf(tile[threadIdx.x][threadIdx.y]);
}

__global__ void concat_bias3(const float* a, const float* b, const float* c,
                             float* o) {
  int i = blockIdx.x * 256 + threadIdx.x;
  if (i >= 3072) return;
  o[i] = (i < 1024) ? a[i] : (i < 2048 ? b[i - 1024] : c[i - 2048]);
}

// ===== shared staging / frag macros (XOR swizzle: both-sides involution) =====
// stage 16KB = 128 rows x 64 cols from global (row-major, ld) into linear LDS.
#define STAGE128(gbase, ld, ldsbase, rowbase)                                 \
  {                                                                           \
    _Pragma("unroll") for (int l_ = 0; l_ < 2; ++l_) {                        \
      const int seg_ = (w << 1) + l_;                                         \
      const int r0_ = (rowbase) + (seg_ << 3);                                \
      const int gr_ = r0_ + (lane >> 3);                                      \
      const int sc_ = ((lane & 7) ^ (lane >> 3)) << 3;                        \
      gload_lds16((gbase) + (size_t)gr_ * (ld) + sc_, (ldsbase) + r0_ * 64);  \
    }                                                                         \
  }

#define LDA_FRAG(dst, tile, rbase)                                            \
  _Pragma("unroll") for (int m_ = 0; m_ < 4; ++m_)                            \
  _Pragma("unroll") for (int kk_ = 0; kk_ < 2; ++kk_) {                       \
    const int row_ = (rbase) + (m_ << 4) + (lane & 15);                       \
    const int ch_ = ((kk_ << 2) + (lane >> 4)) ^ (lane & 7);                  \
    dst[m_][kk_] =                                                            \
        *reinterpret_cast<const bf16x8*>((tile) + row_ * 64 + (ch_ << 3));    \
  }
#define LDB_FRAG(dst, tile, rbase)                                            \
  _Pragma("unroll") for (int n_ = 0; n_ < 2; ++n_)                            \
  _Pragma("unroll") for (int kk_ = 0; kk_ < 2; ++kk_) {                       \
    const int row_ = (rbase) + (n_ << 4) + (lane & 15);                       \
    const int ch_ = ((kk_ << 2) + (lane >> 4)) ^ (lane & 7);                  \
    dst[n_][kk_] =                                                            \
        *reinterpret_cast<const bf16x8*>((tile) + row_ * 64 + (ch_ << 3));    \
  }

// =====================================================================
// gemm256: 256x256 tile, 8 waves (2M x 4N), per-wave 128x64. (m201 template)
// =====================================================================
#define STAGE_A(gbase, ld, ldsbase, h)                                        \
  {                                                                           \
    _Pragma("unroll") for (int l_ = 0; l_ < 2; ++l_) {                        \
      const int seg_ = (w << 1) + l_;                                         \
      const int r0_ = ((seg_ >> 3) << 7) + ((h) << 6) + ((seg_ & 7) << 3);    \
      const int gr_ = r0_ + (lane >> 3);                                      \
      const int sc_ = ((lane & 7) ^ (lane >> 3)) << 3;                        \
      gload_lds16((gbase) + (size_t)gr_ * (ld) + sc_, (ldsbase) + r0_ * 64);  \
    }                                                                         \
  }
#define STAGE_B(gbase, ld, ldsbase, h)                                        \
  {                                                                           \
    _Pragma("unroll") for (int l_ = 0; l_ < 2; ++l_) {                        \
      const int seg_ = (w << 1) + l_;                                         \
      const int r0_ = ((seg_ >> 2) << 6) + ((h) << 5) + ((seg_ & 3) << 3);    \
      const int gr_ = r0_ + (lane >> 3);                                      \
      const int sc_ = ((lane & 7) ^ (lane >> 3)) << 3;                        \
      gload_lds16((gbase) + (size_t)gr_ * (ld) + sc_, (ldsbase) + r0_ * 64);  \
    }                                                                         \
  }

#define MFMA_QUAD(a_, b_, af_, bf_)                                           \
  __builtin_amdgcn_s_setprio(1);                                              \
  _Pragma("unroll") for (int m_ = 0; m_ < 4; ++m_)                            \
  _Pragma("unroll") for (int n_ = 0; n_ < 2; ++n_)                            \
  _Pragma("unroll") for (int kk_ = 0; kk_ < 2; ++kk_)                         \
      acc[(a_) * 4 + m_][(b_) * 2 + n_] =                                     \
          __builtin_amdgcn_mfma_f32_16x16x32_bf16(                            \
              af_[m_][kk_], bf_[n_][kk_], acc[(a_) * 4 + m_][(b_) * 2 + n_],  \
              0, 0, 0);                                                       \
  __builtin_amdgcn_s_setprio(0);

template <typename OutT, bool HAS_BIAS>
__global__ __launch_bounds__(512, 2) void gemm256(
    const unsigned short* __restrict__ A,
    const unsigned short* __restrict__ Bt,
    OutT* __restrict__ C,
    const float* __restrict__ bias,
    int K, int lda, int ldb, int ldc, float scale,
    long sA, long sB, long sC) {
  int bx, by, bz;
  xcd_swz(bx, by, bz);
  A  += (long)bz * sA;
  Bt += (long)bz * sB;
  C  += (long)bz * sC;
  const int n0 = bx << 8;
  const int m0 = by << 8;
  __shared__ __attribute__((aligned(16))) unsigned short lds[2 * 32768];
  const int t = threadIdx.x;
  const int lane = t & 63;
  const int w = t >> 6;
  const int wm = w >> 2, wn = w & 3;
  const unsigned short* gA = A + (size_t)m0 * lda;
  const unsigned short* gB = Bt + (size_t)n0 * ldb;
  const int NT = K >> 6;

  f32x4 acc[8][4];
  const f32x4 vz = {0.f, 0.f, 0.f, 0.f};
#pragma unroll
  for (int i = 0; i < 8; ++i)
#pragma unroll
    for (int j = 0; j < 4; ++j) acc[i][j] = vz;

  {
    unsigned short* a0 = lds;
    unsigned short* b0t = lds + 16384;
    STAGE_A(gA, lda, a0, 0);
    STAGE_B(gB, ldb, b0t, 0);
    STAGE_B(gB, ldb, b0t, 1);
    STAGE_A(gA, lda, a0, 1);
    if (NT > 1) {
      unsigned short* a1 = lds + 32768;
      unsigned short* b1t = lds + 32768 + 16384;
      STAGE_A(gA + 64, lda, a1, 0);
      STAGE_B(gB + 64, ldb, b1t, 0);
      STAGE_B(gB + 64, ldb, b1t, 1);
      asm volatile("s_waitcnt vmcnt(6)" ::: "memory");
    } else {
      asm volatile("s_waitcnt vmcnt(0)" ::: "memory");
    }
  }
  BAR();

  for (int kt = 0; kt < NT; ++kt) {
    unsigned short* at = lds + ((kt & 1) << 15);
    unsigned short* bt = at + 16384;
    unsigned short* atN = lds + (((kt + 1) & 1) << 15);
    const unsigned short* gA1 = gA + (size_t)(kt + 1) * 64;
    const unsigned short* gA2 = gA + (size_t)(kt + 2) * 64;
    const unsigned short* gB2 = gB + (size_t)(kt + 2) * 64;
    const bool st1 = kt + 1 < NT, st2 = kt + 2 < NT;

    bf16x8 af[4][2], b0[2][2], b1[2][2];

    LDA_FRAG(af, at, (wm << 7));
    LDB_FRAG(b0, bt, (wn << 6));
    if (st1) STAGE_A(gA1, lda, atN, 1);
    BAR();
    LGKM0();
    MFMA_QUAD(0, 0, af, b0);
    BAR();

    LDB_FRAG(b1, bt, (wn << 6) + 32);
    if (st2) STAGE_A(gA2, lda, at, 0);
    BAR();
    LGKM0();
    MFMA_QUAD(0, 1, af, b1);
    BAR();

    LDA_FRAG(af, at, (wm << 7) + 64);
    if (st2) STAGE_B(gB2, ldb, bt, 0);
    BAR();
    LGKM0();
    MFMA_QUAD(1, 0, af, b0);
    BAR();

    if (st2) STAGE_B(gB2, ldb, bt, 1);
    if (kt < NT - 3) {
      asm volatile("s_waitcnt vmcnt(6)" ::: "memory");
    } else {
      asm volatile("s_waitcnt vmcnt(0)" ::: "memory");
    }
    BAR();
    MFMA_QUAD(1, 1, af, b1);
    BAR();
  }

  const int crow0 = m0 + (wm << 7) + ((lane >> 4) << 2);
  const int ccol0 = n0 + (wn << 6) + (lane & 15);
#pragma unroll
  for (int mf = 0; mf < 8; ++mf) {
#pragma unroll
    for (int nf = 0; nf < 4; ++nf) {
      const int col = ccol0 + (nf << 4);
      const float bb = HAS_BIAS ? bias[col] : 0.f;
#pragma unroll
      for (int i = 0; i < 4; ++i) {
        const int row = crow0 + (mf << 4) + i;
        const float v = acc[mf][nf][i] * scale + bb;
        if constexpr (sizeof(OutT) == 2) {
          C[(size_t)row * ldc + col] = (OutT)f2bf(v);
        } else {
          C[(size_t)row * ldc + col] = (OutT)v;
        }
      }
    }
  }
}

// =====================================================================
// gemm128: BM=256 x BN=128, 8 waves (4M x 2N), per-wave 64x64, acc[4][4].
// 2 phases/K-tile; per-tile chunks: A=2x16KB, B=1x16KB; LDS 96KB dbuf.
// Staging: B(t+1) in P1 (other buf, over dead t-1 B); A(t+2) in P2 (cur buf,
// A read finished in P1). Counted vmcnt(4) at P2 == tile t+1 landed.
// VSPLIT: blocks with n0>=2048 write V transposed to vt[b][d][s].
// =====================================================================
#define MFMA_QUAD128(b_, af_, bf_)                                            \
  __builtin_amdgcn_s_setprio(1);                                              \
  _Pragma("unroll") for (int m_ = 0; m_ < 4; ++m_)                            \
  _Pragma("unroll") for (int n_ = 0; n_ < 2; ++n_)                            \
  _Pragma("unroll") for (int kk_ = 0; kk_ < 2; ++kk_)                         \
      acc[m_][(b_) * 2 + n_] = __builtin_amdgcn_mfma_f32_16x16x32_bf16(       \
          af_[m_][kk_], bf_[n_][kk_], acc[m_][(b_) * 2 + n_], 0, 0, 0);       \
  __builtin_amdgcn_s_setprio(0);

template <typename OutT, bool HAS_BIAS, bool VSPLIT>
__global__ __launch_bounds__(512, 2) void gemm128(
    const unsigned short* __restrict__ A,
    const unsigned short* __restrict__ Bt,
    OutT* __restrict__ C,
    const float* __restrict__ bias,
    unsigned short* __restrict__ vt,
    int K, int lda, int ldb, int ldc, float scale,
    long sA, long sB, long sC) {
  int bx, by, bz;
  xcd_swz(bx, by, bz);
  A  += (long)bz * sA;
  Bt += (long)bz * sB;
  C  += (long)bz * sC;
  const int n0 = bx << 7;
  const int m0 = by << 8;
  __shared__ __attribute__((aligned(16))) unsigned short lds[2 * 24576];
  const int t = threadIdx.x;
  const int lane = t & 63;
  const int w = t >> 6;
  const int wm = w >> 1, wn = w & 1;
  const unsigned short* gA = A + (size_t)m0 * lda;
  const unsigned short* gB = Bt + (size_t)n0 * ldb;
  const int NT = K >> 6;

  f32x4 acc[4][4];
  const f32x4 vz = {0.f, 0.f, 0.f, 0.f};
#pragma unroll
  for (int i = 0; i < 4; ++i)
#pragma unroll
    for (int j = 0; j < 4; ++j) acc[i][j] = vz;

  // prologue: t0 {A0,A1,B} then A(1); vmcnt(4) leaves A(1) in flight
  {
    unsigned short* a0 = lds;
    unsigned short* b0 = lds + 16384;
    STAGE128(gA, lda, a0, 0);
    STAGE128(gA, lda, a0, 128);
    STAGE128(gB, ldb, b0, 0);
    if (NT > 1) {
      unsigned short* a1 = lds + 24576;
      STAGE128(gA + 64, lda, a1, 0);
      STAGE128(gA + 64, lda, a1, 128);
      asm volatile("s_waitcnt vmcnt(4)" ::: "memory");
    } else {
      asm volatile("s_waitcnt vmcnt(0)" ::: "memory");
    }
  }
  BAR();

  for (int kt = 0; kt < NT; ++kt) {
    const int p = kt & 1;
    unsigned short* at = lds + p * 24576;
    unsigned short* btile = at + 16384;
    unsigned short* atO = lds + (p ^ 1) * 24576;
    const unsigned short* gB1 = gB + (size_t)(kt + 1) * 64;
    const unsigned short* gA2 = gA + (size_t)(kt + 2) * 64;
    const bool st1 = kt + 1 < NT, st2 = kt + 2 < NT;

    bf16x8 af[4][2], b0[2][2], b1[2][2];

    // P1: read A (8) + B-half0 (4); stage B(t+1) into other buffer
    LDA_FRAG(af, at, (wm << 6));
    LDB_FRAG(b0, btile, (wn << 6));
    if (st1) STAGE128(gB1, ldb, atO + 16384, 0);
    BAR();
    LGKM0();
    MFMA_QUAD128(0, af, b0);
    BAR();

    // P2: read B-half1 (4); stage A(t+2) into current buffer; counted vmcnt
    LDB_FRAG(b1, btile, (wn << 6) + 32);
    if (st2) {
      STAGE128(gA2, lda, at, 0);
      STAGE128(gA2, lda, at, 128);
    }
    if (kt < NT - 2) {
      asm volatile("s_waitcnt vmcnt(4)" ::: "memory");
    } else {
      asm volatile("s_waitcnt vmcnt(0)" ::: "memory");
    }
    BAR();
    LGKM0();
    MFMA_QUAD128(1, af, b1);
    BAR();
  }

  const int crow0 = m0 + (wm << 6) + ((lane >> 4) << 2);
  const int ccol0 = n0 + (wn << 6) + (lane & 15);

  if (VSPLIT && n0 >= 2048) {
    // V block: write transposed vt[b][d][s] = v + bias; b from m0 (256-row
    // tiles never cross a 2048-row batch).
    const int b = m0 >> 11;
#pragma unroll
    for (int mf = 0; mf < 4; ++mf) {
#pragma unroll
      for (int nf = 0; nf < 4; ++nf) {
        const int col = ccol0 + (nf << 4);
        const float bb = HAS_BIAS ? bias[col] : 0.f;
        const int d = col - 2048;
        const int s = (crow0 & 2047) + (mf << 4);
        ushort4 o;
        o.x = f2bf(acc[mf][nf][0] * scale + bb);
        o.y = f2bf(acc[mf][nf][1] * scale + bb);
        o.z = f2bf(acc[mf][nf][2] * scale + bb);
        o.w = f2bf(acc[mf][nf][3] * scale + bb);
        *reinterpret_cast<ushort4*>(vt + (((size_t)b << 10) + d) * 2048 + s) = o;
      }
    }
    return;
  }

#pragma unroll
  for (int mf = 0; mf < 4; ++mf) {
#pragma unroll
    for (int nf = 0; nf < 4; ++nf) {
      const int col = ccol0 + (nf << 4);
      const float bb = HAS_BIAS ? bias[col] : 0.f;
#pragma unroll
      for (int i = 0; i < 4; ++i) {
        const int row = crow0 + (mf << 4) + i;
        const float v = acc[mf][nf][i] * scale + bb;
        if constexpr (sizeof(OutT) == 2) {
          C[(size_t)row * ldc + col] = (OutT)f2bf(v);
        } else {
          C[(size_t)row * ldc + col] = (OutT)v;
        }
      }
    }
  }
}

// ---------- row softmax, in place, bf16, one block per row ----------
__global__ __launch_bounds__(256) void softmax_inplace(
    unsigned short* __restrict__ P, int S) {
  const size_t row = blockIdx.x;
  unsigned short* p = P + row * (size_t)S;
  const int t = threadIdx.x;
  const int lane = t & 63, w = t >> 6;
  const uint4 raw = reinterpret_cast<const uint4*>(p)[t];
  unsigned int u[4] = {raw.x, raw.y, raw.z, raw.w};
  float v[8];
#pragma unroll
  for (int j = 0; j < 4; ++j) {
    v[2 * j]     = bf2f((unsigned short)(u[j] & 0xffffu));
    v[2 * j + 1] = bf2f((unsigned short)(u[j] >> 16));
  }
  float mx = v[0];
#pragma unroll
  for (int j = 1; j < 8; ++j) mx = fmaxf(mx, v[j]);
#pragma unroll
  for (int off = 32; off >= 1; off >>= 1) mx = fmaxf(mx, __shfl_xor(mx, off, 64));
  __shared__ float red[4];
  if (lane == 0) red[w] = mx;
  __syncthreads();
  mx = fmaxf(fmaxf(red[0], red[1]), fmaxf(red[2], red[3]));
  float e[8];
  float s = 0.f;
#pragma unroll
  for (int j = 0; j < 8; ++j) { e[j] = __expf(v[j] - mx); s += e[j]; }
#pragma unroll
  for (int off = 32; off >= 1; off >>= 1) s += __shfl_xor(s, off, 64);
  __syncthreads();
  if (lane == 0) red[w] = s;
  __syncthreads();
  s = red[0] + red[1] + red[2] + red[3];
  const float inv = 1.f / s;
  unsigned int o[4];
#pragma unroll
  for (int j = 0; j < 4; ++j)
    o[j] = (unsigned int)f2bf(e[2 * j] * inv) |
           ((unsigned int)f2bf(e[2 * j + 1] * inv) << 16);
  uint4 ov; ov.x = o[0]; ov.y = o[1]; ov.z = o[2]; ov.w = o[3];
  reinterpret_cast<uint4*>(p)[t] = ov;
}

// ---------- launch ----------
extern "C" void kernel_launch(void* const* d_in, const int* in_sizes, int n_in,
                              void* d_out, int out_size, void* d_ws, size_t ws_size,
                              hipStream_t stream) {
  (void)in_sizes; (void)n_in; (void)out_size; (void)ws_size;
  const float* x  = (const float*)d_in[0];
  const float* Wq = (const float*)d_in[1];
  const float* bq = (const float*)d_in[2];
  const float* Wk = (const float*)d_in[3];
  const float* bk = (const float*)d_in[4];
  const float* Wv = (const float*)d_in[5];
  const float* bv = (const float*)d_in[6];
  const float* Wo = (const float*)d_in[7];
  const float* bo = (const float*)d_in[8];
  float* out = (float*)d_out;

  constexpr int B = 4, S = 2048, D = 1024;
  constexpr long BS = (long)B * S;  // 8192
  constexpr size_t MB = 1ull << 20;
  char* ws = (char*)d_ws;
  // workspace map (105 MB):
  unsigned short* xb   = (unsigned short*)(ws + 0);        // 16MB (dead after QKV)
  unsigned short* Wall = (unsigned short*)(ws + 16 * MB);  // 8MB [4][1024][1024]
  float*          bqkv = (float*)(ws + 24 * MB);           // 12KB
  unsigned short* QKVc = (unsigned short*)(ws + 25 * MB);  // 32MB [8192][2048] (Q|K)
  unsigned short* Vt   = (unsigned short*)(ws + 57 * MB);  // 16MB [4][1024][2048]
  unsigned short* Sc   = (unsigned short*)(ws + 73 * MB);  // 32MB
  unsigned short* AO   = (unsigned short*)(ws + 0);        // 16MB (over xb)

  const float scale = 0.03125f;  // 1/sqrt(1024)

  cvt_f32_to_bf16<<<(BS * D / 4 + 255) / 256, 256, 0, stream>>>(x, xb, BS * D / 4);
  transpose_w4<<<dim3(32, 32, 4), dim3(32, 32), 0, stream>>>(Wq, Wk, Wv, Wo, Wall);
  concat_bias3<<<12, 256, 0, stream>>>(bq, bk, bv, bqkv);

  // fused QKV projection: N=3072, Q|K -> QKVc[8192][2048], V -> Vt transposed
  gemm128<unsigned short, true, true><<<dim3(24, 32, 1), 512, 0, stream>>>(
      xb, Wall, QKVc, bqkv, Vt, D, D, D, 2048, 1.f, 0, 0, 0);

  // scores[b] = scale * Q[b] @ K[b]^T   [2048 x 2048]
  gemm256<unsigned short, false><<<dim3(S / 256, S / 256, B), 512, 0, stream>>>(
      QKVc + 0, QKVc + 1024, Sc, nullptr, D, 2048, 2048, S, scale,
      (long)S * 2048, (long)S * 2048, (long)S * S);

  softmax_inplace<<<B * S, 256, 0, stream>>>(Sc, S);

  // attn_out[b] = P[b] @ V[b] via Vt: M=2048, N=1024, K=2048
  gemm128<unsigned short, false, false><<<dim3(8, 8, 4), 512, 0, stream>>>(
      Sc, Vt, AO, nullptr, nullptr, S, S, S, D, 1.f,
      (long)S * S, (long)D * S, (long)S * D);

  // out = AO @ Wot^T + bo (fp32), M=8192, N=1024
  gemm128<float, true, false><<<dim3(8, 32, 1), 512, 0, stream>>>(
      AO, Wall + 3 * 1024 * 1024, out, bo, nullptr, D, D, D, D, 1.f, 0, 0, 0);
}